// Round 1
// baseline (480.337 us; speedup 1.0000x reference)
//
#include <hip/hip_runtime.h>
#include <hip/hip_bf16.h>
#include <math.h>

#define B_   32
#define S_   512
#define SxS  (S_ * S_)
#define LOG2E 1.4426950408889634f

using frag_ab = __attribute__((ext_vector_type(8))) short;   // 8 bf16 = 4 VGPR
using frag_cd = __attribute__((ext_vector_type(4))) float;   // 4 fp32 acc

__device__ inline short f2bf(float x) {
    __hip_bfloat16 h = __float2bfloat16(x);
    return *reinterpret_cast<short*>(&h);
}
__device__ inline float bf2f(short s) {
    __hip_bfloat16 h = *reinterpret_cast<__hip_bfloat16*>(&s);
    return __bfloat162float(h);
}

// async global->LDS, 16B per lane. LDS dest must be wave-uniform base.
__device__ __forceinline__ void async16(const short* g, short* l) {
    __builtin_amdgcn_global_load_lds(
        (const __attribute__((address_space(1))) void*)g,
        (__attribute__((address_space(3))) void*)l,
        16, 0, 0);
}

// ---------------------------------------------------------------------------
// k_prep: reads A/B fp32 once per element. Produces:
//   1) Xt[d][i]  bf16 transposed (V-operand for k_pv), unscaled
//   2) P (PA or PB): packed hi/lo bf16 planes, layout
//        P[row][window W (32 k's)][slot s (16B = 8 shorts)]
//      slot 2q   = hi of k = W*32 + q*8 .. +8
//      slot 2q+1 = lo of same range
//      stored at chunk position (slot ^ (row&7))  -> after linear
//      global_load_lds staging, ds_read_b128 frag reads are conflict-free.
//      PA additionally pre-scaled by LOG2E (so exp() -> exp2() downstream).
// ---------------------------------------------------------------------------
__global__ __launch_bounds__(256) void k_prep(const float* __restrict__ A,
                                              const float* __restrict__ Bm,
                                              short* __restrict__ PA,
                                              short* __restrict__ PB,
                                              short* __restrict__ At,
                                              short* __restrict__ Bt)
{
    const int z   = blockIdx.z;          // 0..63
    const int b   = z & 31;
    const int isB = z >> 5;
    const float* X = (isB ? Bm : A) + (size_t)b * SxS;
    short* P  = (isB ? PB : PA) + (size_t)b * (S_ * 1024);
    short* Xt = (isB ? Bt : At) + (size_t)b * SxS;
    const float scale = isB ? 1.0f : LOG2E;

    const int i0 = blockIdx.y * 64, d0 = blockIdx.x * 64;

    __shared__ short T[64][68];          // transpose staging, pitch 68 (8B rows)

    const int sl = threadIdx.x & 7;      // d-slot: covers d0 + sl*8 .. +8
    const int il = threadIdx.x >> 3;     // 0..31

    #pragma unroll
    for (int p = 0; p < 2; ++p) {
        const int i    = il + 32 * p;
        const int rowg = i0 + i;
        const float* src = X + (size_t)rowg * S_ + d0 + sl * 8;
        const float4 v0 = *(const float4*)(src);
        const float4 v1 = *(const float4*)(src + 4);

        // transpose path (unscaled bf16)
        T[sl * 8 + 0][i] = f2bf(v0.x); T[sl * 8 + 1][i] = f2bf(v0.y);
        T[sl * 8 + 2][i] = f2bf(v0.z); T[sl * 8 + 3][i] = f2bf(v0.w);
        T[sl * 8 + 4][i] = f2bf(v1.x); T[sl * 8 + 5][i] = f2bf(v1.y);
        T[sl * 8 + 6][i] = f2bf(v1.z); T[sl * 8 + 7][i] = f2bf(v1.w);

        // hi/lo split path (scaled)
        const float xs[8] = {v0.x, v0.y, v0.z, v0.w, v1.x, v1.y, v1.z, v1.w};
        frag_ab hi, lo;
        #pragma unroll
        for (int j = 0; j < 8; ++j) {
            const float x = xs[j] * scale;
            const short h = f2bf(x);
            hi[j] = h;
            lo[j] = f2bf(x - bf2f(h));
        }
        const int W = (d0 >> 5) + (sl >> 2);
        const int q = sl & 3;
        short* base = P + (size_t)rowg * 1024 + W * 64;
        *(frag_ab*)(base + (((2 * q)     ^ (rowg & 7)) * 8)) = hi;
        *(frag_ab*)(base + (((2 * q + 1) ^ (rowg & 7)) * 8)) = lo;
    }
    __syncthreads();

    const int r = threadIdx.x >> 4, c = threadIdx.x & 15;
    #pragma unroll
    for (int p = 0; p < 4; ++p) {
        const int d = r + p * 16;
        *(short4*)(Xt + (size_t)(d0 + d) * S_ + i0 + c * 4) = *(short4*)&T[d][c * 4];
    }
}

// ---------------------------------------------------------------------------
// e' = (LOG2E*A)·B^T via hi/lo bf16 MFMA (3 products). m97 structure:
// global_load_lds(16B) staging into linear LDS, XOR-swizzled ds_read_b128,
// zero VALU in the K-loop. 128x128 tile, BK=32, 4 waves. Writes E and Et.
// ---------------------------------------------------------------------------
__global__ __launch_bounds__(256) void k_gemm_e(const short* __restrict__ PA,
                                                const short* __restrict__ PB,
                                                float* __restrict__ E,
                                                float* __restrict__ Et)
{
    // bijective XCD swizzle over 512 blocks: each XCD owns 4 whole batches
    const int lin     = blockIdx.x + (blockIdx.y << 2) + (blockIdx.z << 4);
    const int logical = ((lin & 7) << 6) + (lin >> 3);
    const int b  = logical >> 4;
    const int i0 = ((logical >> 2) & 3) * 128;
    const int j0 = (logical & 3) * 128;

    const short* Ab = PA + (size_t)b * (S_ * 1024);
    const short* Bb = PB + (size_t)b * (S_ * 1024);
    float* Eb  = E  + (size_t)b * SxS;
    float* Etb = Et + (size_t)b * SxS;

    __shared__ __align__(16) short As[128][64];   // 16 KB, linear (gload_lds dest)
    __shared__ __align__(16) short Bs[128][64];   // 16 KB

    const int tid  = threadIdx.x;
    const int wave = tid >> 6, lane = tid & 63;
    const int wr   = wave >> 1, wc = wave & 1;
    const int q    = lane >> 4, m = lane & 15;
    const int srow = lane >> 3, schunk = lane & 7;   // staging geometry

    frag_cd zero = {0.f, 0.f, 0.f, 0.f};
    frag_cd acc[4][4];
    #pragma unroll
    for (int i = 0; i < 4; ++i)
        #pragma unroll
        for (int j = 0; j < 4; ++j) acc[i][j] = zero;

    for (int k0 = 0; k0 < S_; k0 += 32) {
        const int W = k0 >> 5;
        __syncthreads();                       // LDS free (prev iter consumed)
        #pragma unroll
        for (int p = 0; p < 4; ++p) {
            const int seg    = wave * 4 + p;   // 8-row segment, wave-uniform
            const int rowg_a = i0 + seg * 8 + srow;
            const int rowg_b = j0 + seg * 8 + srow;
            async16(Ab + (size_t)rowg_a * 1024 + W * 64 + schunk * 8, &As[seg * 8][0]);
            async16(Bb + (size_t)rowg_b * 1024 + W * 64 + schunk * 8, &Bs[seg * 8][0]);
        }
        __syncthreads();                       // drains vmcnt -> tiles visible

        frag_ab ah[4], al[4], bh[4], bl[4];
        #pragma unroll
        for (int t = 0; t < 4; ++t) {
            const int ra = wr * 64 + t * 16 + m;
            const int rb = wc * 64 + t * 16 + m;
            ah[t] = *(const frag_ab*)&As[ra][((2 * q)     ^ (ra & 7)) * 8];
            al[t] = *(const frag_ab*)&As[ra][((2 * q + 1) ^ (ra & 7)) * 8];
            bh[t] = *(const frag_ab*)&Bs[rb][((2 * q)     ^ (rb & 7)) * 8];
            bl[t] = *(const frag_ab*)&Bs[rb][((2 * q + 1) ^ (rb & 7)) * 8];
        }
        #pragma unroll
        for (int mt = 0; mt < 4; ++mt)
            #pragma unroll
            for (int nt = 0; nt < 4; ++nt) {
                acc[mt][nt] = __builtin_amdgcn_mfma_f32_16x16x32_bf16(ah[mt], bh[nt], acc[mt][nt], 0, 0, 0);
                acc[mt][nt] = __builtin_amdgcn_mfma_f32_16x16x32_bf16(ah[mt], bl[nt], acc[mt][nt], 0, 0, 0);
                acc[mt][nt] = __builtin_amdgcn_mfma_f32_16x16x32_bf16(al[mt], bh[nt], acc[mt][nt], 0, 0, 0);
            }
    }

    #pragma unroll
    for (int mt = 0; mt < 4; ++mt)
        #pragma unroll
        for (int nt = 0; nt < 4; ++nt) {
            const int rb  = i0 + wr * 64 + mt * 16 + q * 4;
            const int col = j0 + wc * 64 + nt * 16 + m;
            float4 v = make_float4(acc[mt][nt][0], acc[mt][nt][1],
                                   acc[mt][nt][2], acc[mt][nt][3]);
            Eb[(size_t)(rb + 0) * S_ + col] = v.x;
            Eb[(size_t)(rb + 1) * S_ + col] = v.y;
            Eb[(size_t)(rb + 2) * S_ + col] = v.z;
            Eb[(size_t)(rb + 3) * S_ + col] = v.w;
            *(float4*)(Etb + (size_t)col * S_ + rb) = v;   // transposed copy
        }
}

// ---------------------------------------------------------------------------
// Row stats on the pre-scaled E (exp2 domain): max and 1/sum(exp2(e'-m)).
// blockIdx.y selects E (row side) vs Et (col side). One wave per row.
// ---------------------------------------------------------------------------
__global__ __launch_bounds__(256) void k_rowstats(const float* __restrict__ E,
                                                  const float* __restrict__ Et,
                                                  float* __restrict__ rmax,
                                                  float* __restrict__ rinv,
                                                  float* __restrict__ cmax,
                                                  float* __restrict__ cinv)
{
    const float* src = blockIdx.y ? Et : E;
    float* pm = blockIdx.y ? cmax : rmax;
    float* pi = blockIdx.y ? cinv : rinv;

    const int row  = blockIdx.x * 4 + (threadIdx.x >> 6);
    const int lane = threadIdx.x & 63;
    const float* er = src + (size_t)row * S_;

    float4 v0 = *(const float4*)(er + lane * 4);
    float4 v1 = *(const float4*)(er + 256 + lane * 4);

    float m = fmaxf(fmaxf(fmaxf(v0.x, v0.y), fmaxf(v0.z, v0.w)),
                    fmaxf(fmaxf(v1.x, v1.y), fmaxf(v1.z, v1.w)));
    #pragma unroll
    for (int off = 32; off >= 1; off >>= 1)
        m = fmaxf(m, __shfl_xor(m, off));

    float s = exp2f(v0.x - m) + exp2f(v0.y - m)
            + exp2f(v0.z - m) + exp2f(v0.w - m)
            + exp2f(v1.x - m) + exp2f(v1.y - m)
            + exp2f(v1.z - m) + exp2f(v1.w - m);
    #pragma unroll
    for (int off = 32; off >= 1; off >>= 1)
        s += __shfl_xor(s, off);

    if (lane == 0) { pm[row] = m; pi[row] = 1.0f / s; }
}

// ---------------------------------------------------------------------------
// out_rows = softmax_row(E') · V, fused epilogue writing the 4 concat
// sections. Both sides (m_a / m_b) in one launch via blockIdx decode.
// ---------------------------------------------------------------------------
__global__ __launch_bounds__(256) void k_pv(const float* __restrict__ E,
                                            const float* __restrict__ Et,
                                            const float* __restrict__ rmx_,
                                            const float* __restrict__ rin_,
                                            const float* __restrict__ cmx_,
                                            const float* __restrict__ cin_,
                                            const short* __restrict__ At,
                                            const short* __restrict__ Bt,
                                            const float* __restrict__ A,
                                            const float* __restrict__ Bm,
                                            float* __restrict__ Ma,
                                            float* __restrict__ Mb)
{
    // bijective XCD swizzle over 1024 blocks
    const int lin     = blockIdx.x + (blockIdx.y << 2) + (blockIdx.z << 4);
    const int logical = ((lin & 7) << 7) + (lin >> 3);
    const int zz   = logical >> 4;
    const int side = zz >> 5, b = zz & 31;
    const int r0 = ((logical >> 2) & 3) * 128, d0 = (logical & 3) * 128;

    const float* Eb  = (side ? Et : E) + (size_t)b * SxS;
    const float* rmb = (side ? cmx_ : rmx_) + b * S_;
    const float* rib = (side ? cin_ : rin_) + b * S_;
    const short* Vb  = (side ? At : Bt) + (size_t)b * SxS;
    const float* Xb  = (side ? Bm : A) + (size_t)b * SxS;
    float* Ob = (side ? Mb : Ma) + (size_t)b * S_ * 2048;

    __shared__ __align__(16) short Ps[128][40], Vs[128][40];   // 20 KB

    const int tid  = threadIdx.x;
    const int kc   = tid & 7, lr = tid >> 3;     // P loader
    const int kb   = tid & 3, dr = tid >> 2;     // V loader
    const int wave = tid >> 6, lane = tid & 63;
    const int wr   = wave >> 1, wc = wave & 1;
    const int q    = lane >> 4, m = lane & 15;

    float rml[4];
    #pragma unroll
    for (int p = 0; p < 4; ++p) rml[p] = rmb[r0 + lr + 32 * p];

    frag_cd zero = {0.f, 0.f, 0.f, 0.f};
    frag_cd acc[4][4];
    #pragma unroll
    for (int i = 0; i < 4; ++i)
        #pragma unroll
        for (int j = 0; j < 4; ++j) acc[i][j] = zero;

    for (int k0 = 0; k0 < S_; k0 += 32) {
        float4 ev[4];
        #pragma unroll
        for (int p = 0; p < 4; ++p)
            ev[p] = *(const float4*)(Eb + (size_t)(r0 + lr + 32 * p) * S_ + k0 + kc * 4);
        frag_ab vv[2];
        #pragma unroll
        for (int p = 0; p < 2; ++p)
            vv[p] = *(const frag_ab*)(Vb + (size_t)(d0 + dr + 64 * p) * S_ + k0 + kb * 8);

        __syncthreads();
        #pragma unroll
        for (int p = 0; p < 4; ++p) {
            short4 pv;
            pv.x = f2bf(exp2f(ev[p].x - rml[p]));
            pv.y = f2bf(exp2f(ev[p].y - rml[p]));
            pv.z = f2bf(exp2f(ev[p].z - rml[p]));
            pv.w = f2bf(exp2f(ev[p].w - rml[p]));
            *(short4*)&Ps[lr + 32 * p][kc * 4] = pv;
        }
        #pragma unroll
        for (int p = 0; p < 2; ++p)
            *(frag_ab*)&Vs[dr + 64 * p][kb * 8] = vv[p];
        __syncthreads();

        frag_ab af[4], bfr[4];
        #pragma unroll
        for (int t = 0; t < 4; ++t) {
            af[t]  = *(const frag_ab*)&Ps[wr * 64 + t * 16 + m][q * 8];
            bfr[t] = *(const frag_ab*)&Vs[wc * 64 + t * 16 + m][q * 8];
        }
        #pragma unroll
        for (int mt = 0; mt < 4; ++mt)
            #pragma unroll
            for (int nt = 0; nt < 4; ++nt)
                acc[mt][nt] = __builtin_amdgcn_mfma_f32_16x16x32_bf16(af[mt], bfr[nt], acc[mt][nt], 0, 0, 0);
    }

    #pragma unroll
    for (int mt = 0; mt < 4; ++mt)
        #pragma unroll
        for (int nt = 0; nt < 4; ++nt) {
            const int rb  = r0 + wr * 64 + mt * 16 + q * 4;
            const int col = d0 + wc * 64 + nt * 16 + m;
            #pragma unroll
            for (int r = 0; r < 4; ++r) {
                const int row = rb + r;
                const float s  = rib[row];
                const float at = acc[mt][nt][r] * s;
                const float xv = Xb[(size_t)row * S_ + col];
                float* o = Ob + (size_t)row * 2048 + col;
                o[0]    = xv;
                o[512]  = at;
                o[1024] = xv - at;
                o[1536] = xv * at;
            }
        }
}

// ---------------------------------------------------------------------------
extern "C" void kernel_launch(void* const* d_in, const int* in_sizes, int n_in,
                              void* d_out, int out_size, void* d_ws, size_t ws_size,
                              hipStream_t stream)
{
    const float* A  = (const float*)d_in[0];   // a_bar [32,512,512]
    const float* Bm = (const float*)d_in[1];   // b_bar [32,512,512]
    float* Ma = (float*)d_out;                             // [32,512,2048]
    float* Mb = Ma + (size_t)B_ * S_ * 2048;               // [32,512,2048]

    // ws layout (unchanged from verified version, ~101 MB):
    float* E    = (float*)d_ws;
    float* Et   = E + (size_t)B_ * SxS;
    short* At   = (short*)(Et + (size_t)B_ * SxS);
    short* Bt   = At + (size_t)B_ * SxS;
    float* rmax = (float*)(Bt + (size_t)B_ * SxS);
    float* rinv = rmax + B_ * S_;
    float* cmax = rinv + B_ * S_;
    float* cinv = cmax + B_ * S_;

    // PA/PB packed hi/lo planes are scratch inside the OUTPUT buffer:
    // dead after k_gemm_e, fully overwritten by k_pv. 67 MB << Ma's 268 MB.
    short* PA = (short*)d_out;
    short* PB = PA + (size_t)B_ * S_ * 1024;

    k_prep    <<<dim3(8, 8, 64),  256, 0, stream>>>(A, Bm, PA, PB, At, Bt);
    k_gemm_e  <<<dim3(4, 4, 32),  256, 0, stream>>>(PA, PB, E, Et);
    k_rowstats<<<dim3(4096, 2),   256, 0, stream>>>(E, Et, rmax, rinv, cmax, cinv);
    k_pv      <<<dim3(4, 4, 64),  256, 0, stream>>>(E, Et, rmax, rinv, cmax, cinv,
                                                    At, Bt, A, Bm, Ma, Mb);
}

// Round 2
// 469.581 us; speedup vs baseline: 1.0229x; 1.0229x over previous
//
#include <hip/hip_runtime.h>
#include <hip/hip_bf16.h>
#include <math.h>

#define B_   32
#define S_   512
#define SxS  (S_ * S_)
#define LOG2E 1.4426950408889634f

using frag_ab = __attribute__((ext_vector_type(8))) short;   // 8 bf16 = 4 VGPR
using frag_cd = __attribute__((ext_vector_type(4))) float;   // 4 fp32 acc

__device__ inline short f2bf(float x) {
    __hip_bfloat16 h = __float2bfloat16(x);
    return *reinterpret_cast<short*>(&h);
}
__device__ inline float bf2f(short s) {
    __hip_bfloat16 h = *reinterpret_cast<__hip_bfloat16*>(&s);
    return __bfloat162float(h);
}

// async global->LDS, 16B per lane. LDS dest must be wave-uniform base.
__device__ __forceinline__ void async16(const short* g, short* l) {
    __builtin_amdgcn_global_load_lds(
        (const __attribute__((address_space(1))) void*)g,
        (__attribute__((address_space(3))) void*)l,
        16, 0, 0);
}

// ---------------------------------------------------------------------------
// k_prep: reads A/B fp32 once. Produces:
//   1) PA/PB: packed hi/lo bf16 planes for the e-GEMM (PA pre-scaled LOG2E).
//      P[row][W (32 k)][slot s: 2q=hi,2q+1=lo, stored at s^(row&7)]
//   2) Va/Vb: bf16 transposed V-planes Vp[d][W (64 k=i)][chunk^(d&7)]
//      (gload_lds-ready layout for k_pv's B-operand).
// ---------------------------------------------------------------------------
__global__ __launch_bounds__(256) void k_prep(const float* __restrict__ A,
                                              const float* __restrict__ Bm,
                                              short* __restrict__ PA,
                                              short* __restrict__ PB,
                                              short* __restrict__ Va,
                                              short* __restrict__ Vb)
{
    const int z   = blockIdx.z;          // 0..63
    const int b   = z & 31;
    const int isB = z >> 5;
    const float* X = (isB ? Bm : A) + (size_t)b * SxS;
    short* P  = (isB ? PB : PA) + (size_t)b * (S_ * 1024);
    short* Vp = (isB ? Vb : Va) + (size_t)b * SxS;
    const float scale = isB ? 1.0f : LOG2E;

    const int i0 = blockIdx.y * 64, d0 = blockIdx.x * 64;

    __shared__ short T[64][72];          // [d_local][i_local], 144B rows (16B-mult)

    const int sl = threadIdx.x & 7;      // d-chunk: d0 + sl*8 .. +8
    const int il = threadIdx.x >> 3;     // 0..31

    #pragma unroll
    for (int p = 0; p < 2; ++p) {
        const int i    = il + 32 * p;
        const int rowg = i0 + i;
        const float* src = X + (size_t)rowg * S_ + d0 + sl * 8;
        const float4 v0 = *(const float4*)(src);
        const float4 v1 = *(const float4*)(src + 4);

        // transpose staging (unscaled bf16)
        T[sl * 8 + 0][i] = f2bf(v0.x); T[sl * 8 + 1][i] = f2bf(v0.y);
        T[sl * 8 + 2][i] = f2bf(v0.z); T[sl * 8 + 3][i] = f2bf(v0.w);
        T[sl * 8 + 4][i] = f2bf(v1.x); T[sl * 8 + 5][i] = f2bf(v1.y);
        T[sl * 8 + 6][i] = f2bf(v1.z); T[sl * 8 + 7][i] = f2bf(v1.w);

        // hi/lo split (scaled) for the e-GEMM planes
        const float xs[8] = {v0.x, v0.y, v0.z, v0.w, v1.x, v1.y, v1.z, v1.w};
        frag_ab hi, lo;
        #pragma unroll
        for (int j = 0; j < 8; ++j) {
            const float x = xs[j] * scale;
            const short h = f2bf(x);
            hi[j] = h;
            lo[j] = f2bf(x - bf2f(h));
        }
        const int W = (d0 >> 5) + (sl >> 2);
        const int q = sl & 3;
        short* base = P + (size_t)rowg * 1024 + W * 64;
        *(frag_ab*)(base + (((2 * q)     ^ (rowg & 7)) * 8)) = hi;
        *(frag_ab*)(base + (((2 * q + 1) ^ (rowg & 7)) * 8)) = lo;
    }
    __syncthreads();

    // V-plane write: thread owns (d, physical chunk pc); logical i-chunk = pc,
    // stored at swizzled slot pc^(dg&7). 16B LDS reads, coalesced 128B stores.
    const int pc = threadIdx.x & 7, dl = threadIdx.x >> 3;
    #pragma unroll
    for (int p = 0; p < 2; ++p) {
        const int d  = dl + 32 * p;
        const int dg = d0 + d;
        frag_ab t = *(const frag_ab*)&T[d][pc * 8];
        *(frag_ab*)(Vp + (size_t)dg * 512 + i0 + ((pc ^ (dg & 7)) * 8)) = t;
    }
}

// ---------------------------------------------------------------------------
// e' = (LOG2E*A)·B^T via hi/lo bf16 MFMA (3 products). m97 structure:
// global_load_lds(16B) staging into linear LDS, XOR-swizzled ds_read_b128,
// zero VALU in the K-loop. 128x128 tile, BK=32, 4 waves. Writes E and Et.
// ---------------------------------------------------------------------------
__global__ __launch_bounds__(256) void k_gemm_e(const short* __restrict__ PA,
                                                const short* __restrict__ PB,
                                                float* __restrict__ E,
                                                float* __restrict__ Et)
{
    // bijective XCD swizzle over 512 blocks
    const int lin     = blockIdx.x + (blockIdx.y << 2) + (blockIdx.z << 4);
    const int logical = ((lin & 7) << 6) + (lin >> 3);
    const int b  = logical >> 4;
    const int i0 = ((logical >> 2) & 3) * 128;
    const int j0 = (logical & 3) * 128;

    const short* Ab = PA + (size_t)b * (S_ * 1024);
    const short* Bb = PB + (size_t)b * (S_ * 1024);
    float* Eb  = E  + (size_t)b * SxS;
    float* Etb = Et + (size_t)b * SxS;

    __shared__ __align__(16) short As[128][64];   // 16 KB, linear (gload_lds dest)
    __shared__ __align__(16) short Bs[128][64];   // 16 KB

    const int tid  = threadIdx.x;
    const int wave = tid >> 6, lane = tid & 63;
    const int wr   = wave >> 1, wc = wave & 1;
    const int q    = lane >> 4, m = lane & 15;
    const int srow = lane >> 3, schunk = lane & 7;

    frag_cd zero = {0.f, 0.f, 0.f, 0.f};
    frag_cd acc[4][4];
    #pragma unroll
    for (int i = 0; i < 4; ++i)
        #pragma unroll
        for (int j = 0; j < 4; ++j) acc[i][j] = zero;

    for (int k0 = 0; k0 < S_; k0 += 32) {
        const int W = k0 >> 5;
        __syncthreads();
        #pragma unroll
        for (int p = 0; p < 4; ++p) {
            const int seg    = wave * 4 + p;
            const int rowg_a = i0 + seg * 8 + srow;
            const int rowg_b = j0 + seg * 8 + srow;
            async16(Ab + (size_t)rowg_a * 1024 + W * 64 + schunk * 8, &As[seg * 8][0]);
            async16(Bb + (size_t)rowg_b * 1024 + W * 64 + schunk * 8, &Bs[seg * 8][0]);
        }
        __syncthreads();

        frag_ab ah[4], al[4], bh[4], bl[4];
        #pragma unroll
        for (int t = 0; t < 4; ++t) {
            const int ra = wr * 64 + t * 16 + m;
            const int rb = wc * 64 + t * 16 + m;
            ah[t] = *(const frag_ab*)&As[ra][((2 * q)     ^ (ra & 7)) * 8];
            al[t] = *(const frag_ab*)&As[ra][((2 * q + 1) ^ (ra & 7)) * 8];
            bh[t] = *(const frag_ab*)&Bs[rb][((2 * q)     ^ (rb & 7)) * 8];
            bl[t] = *(const frag_ab*)&Bs[rb][((2 * q + 1) ^ (rb & 7)) * 8];
        }
        #pragma unroll
        for (int mt = 0; mt < 4; ++mt)
            #pragma unroll
            for (int nt = 0; nt < 4; ++nt) {
                acc[mt][nt] = __builtin_amdgcn_mfma_f32_16x16x32_bf16(ah[mt], bh[nt], acc[mt][nt], 0, 0, 0);
                acc[mt][nt] = __builtin_amdgcn_mfma_f32_16x16x32_bf16(ah[mt], bl[nt], acc[mt][nt], 0, 0, 0);
                acc[mt][nt] = __builtin_amdgcn_mfma_f32_16x16x32_bf16(al[mt], bh[nt], acc[mt][nt], 0, 0, 0);
            }
    }

    #pragma unroll
    for (int mt = 0; mt < 4; ++mt)
        #pragma unroll
        for (int nt = 0; nt < 4; ++nt) {
            const int rb  = i0 + wr * 64 + mt * 16 + q * 4;
            const int col = j0 + wc * 64 + nt * 16 + m;
            float4 v = make_float4(acc[mt][nt][0], acc[mt][nt][1],
                                   acc[mt][nt][2], acc[mt][nt][3]);
            Eb[(size_t)(rb + 0) * S_ + col] = v.x;
            Eb[(size_t)(rb + 1) * S_ + col] = v.y;
            Eb[(size_t)(rb + 2) * S_ + col] = v.z;
            Eb[(size_t)(rb + 3) * S_ + col] = v.w;
            *(float4*)(Etb + (size_t)col * S_ + rb) = v;   // transposed copy
        }
}

// ---------------------------------------------------------------------------
// k_softp: per row of E (or Et): max + sum of exp2, write 1/sum, and write
// P = bf16(exp2(e - m)) IN-PLACE into the first 1 KB of the row, in the
// swizzled-slot plane layout k_pv's gload_lds staging expects.
// Safe in-place: each row owned by one wave; loads complete before stores.
// ---------------------------------------------------------------------------
__global__ __launch_bounds__(256) void k_softp(float* __restrict__ E,
                                               float* __restrict__ Et,
                                               float* __restrict__ rinv,
                                               float* __restrict__ cinv)
{
    float* buf = blockIdx.y ? Et : E;
    float* piv = blockIdx.y ? cinv : rinv;

    const int row  = blockIdx.x * 4 + (threadIdx.x >> 6);   // 0..16383 flat
    const int lane = threadIdx.x & 63;
    float* er = buf + (size_t)row * S_;

    const float4 v0 = *(const float4*)(er + lane * 8);
    const float4 v1 = *(const float4*)(er + lane * 8 + 4);
    const float xs[8] = {v0.x, v0.y, v0.z, v0.w, v1.x, v1.y, v1.z, v1.w};

    float m = xs[0];
    #pragma unroll
    for (int j = 1; j < 8; ++j) m = fmaxf(m, xs[j]);
    #pragma unroll
    for (int off = 32; off >= 1; off >>= 1) m = fmaxf(m, __shfl_xor(m, off));

    float p[8], s = 0.f;
    #pragma unroll
    for (int j = 0; j < 8; ++j) { p[j] = exp2f(xs[j] - m); s += p[j]; }
    #pragma unroll
    for (int off = 32; off >= 1; off >>= 1) s += __shfl_xor(s, off);

    frag_ab out;
    #pragma unroll
    for (int j = 0; j < 8; ++j) out[j] = f2bf(p[j]);

    short* pr = (short*)buf + (size_t)row * 1024;           // row base, 2KB pitch
    const int W = lane >> 3, slt = (lane & 7) ^ (row & 7);
    *(frag_ab*)(pr + W * 64 + slt * 8) = out;
    if (lane == 0) piv[row] = 1.0f / s;
}

// ---------------------------------------------------------------------------
// k_pv: at = (P · V) * rinv, pure zero-VALU-in-loop GEMM. BK=64, gload_lds
// staging of P-plane (in E buffer, 1024-short pitch) and V-plane, swizzled
// ds_read_b128 fragments, 32 MFMA/wave/K-step. Fused 4-section epilogue.
// Both sides in one launch.
// ---------------------------------------------------------------------------
__global__ __launch_bounds__(256) void k_pv(const float* __restrict__ E,
                                            const float* __restrict__ Et,
                                            const float* __restrict__ rin_,
                                            const float* __restrict__ cin_,
                                            const short* __restrict__ Va,
                                            const short* __restrict__ Vb,
                                            const float* __restrict__ A,
                                            const float* __restrict__ Bm,
                                            float* __restrict__ Ma,
                                            float* __restrict__ Mb)
{
    // bijective XCD swizzle over 1024 blocks
    const int lin     = blockIdx.x + (blockIdx.y << 2) + (blockIdx.z << 4);
    const int logical = ((lin & 7) << 7) + (lin >> 3);
    const int zz   = logical >> 4;
    const int side = zz >> 5, b = zz & 31;
    const int r0 = ((logical >> 2) & 3) * 128, d0 = (logical & 3) * 128;

    const short* Pb  = (const short*)(side ? Et : E) + (size_t)b * (S_ * 1024);
    const float* rib = (side ? cin_ : rin_) + b * S_;
    const short* Vp  = (side ? Va : Vb) + (size_t)b * SxS;
    const float* Xb  = (side ? Bm : A) + (size_t)b * SxS;
    float* Ob = (side ? Mb : Ma) + (size_t)b * S_ * 2048;

    __shared__ __align__(16) short Ps[128][64];   // 16 KB
    __shared__ __align__(16) short Vs[128][64];   // 16 KB

    const int tid  = threadIdx.x;
    const int wave = tid >> 6, lane = tid & 63;
    const int wr   = wave >> 1, wc = wave & 1;
    const int q    = lane >> 4, m = lane & 15;
    const int srow = lane >> 3, schunk = lane & 7;

    frag_cd zero = {0.f, 0.f, 0.f, 0.f};
    frag_cd acc[4][4];
    #pragma unroll
    for (int i = 0; i < 4; ++i)
        #pragma unroll
        for (int j = 0; j < 4; ++j) acc[i][j] = zero;

    for (int k0 = 0; k0 < S_; k0 += 64) {
        const int W = k0 >> 6;
        __syncthreads();
        #pragma unroll
        for (int p = 0; p < 4; ++p) {
            const int seg = wave * 4 + p;
            async16(Pb + (size_t)(r0 + seg * 8 + srow) * 1024 + W * 64 + schunk * 8,
                    &Ps[seg * 8][0]);
            async16(Vp + (size_t)(d0 + seg * 8 + srow) * 512  + W * 64 + schunk * 8,
                    &Vs[seg * 8][0]);
        }
        __syncthreads();

        #pragma unroll
        for (int kk = 0; kk < 2; ++kk) {
            frag_ab af[4], bfr[4];
            #pragma unroll
            for (int t = 0; t < 4; ++t) {
                const int ra = wr * 64 + t * 16 + m;
                const int rb = wc * 64 + t * 16 + m;
                af[t]  = *(const frag_ab*)&Ps[ra][(((kk * 4 + q) ^ (ra & 7)) * 8)];
                bfr[t] = *(const frag_ab*)&Vs[rb][(((kk * 4 + q) ^ (rb & 7)) * 8)];
            }
            #pragma unroll
            for (int mt = 0; mt < 4; ++mt)
                #pragma unroll
                for (int nt = 0; nt < 4; ++nt)
                    acc[mt][nt] = __builtin_amdgcn_mfma_f32_16x16x32_bf16(af[mt], bfr[nt], acc[mt][nt], 0, 0, 0);
        }
    }

    #pragma unroll
    for (int mt = 0; mt < 4; ++mt)
        #pragma unroll
        for (int nt = 0; nt < 4; ++nt) {
            const int rb  = r0 + wr * 64 + mt * 16 + q * 4;
            const int col = d0 + wc * 64 + nt * 16 + m;
            #pragma unroll
            for (int r = 0; r < 4; ++r) {
                const int row = rb + r;
                const float at = acc[mt][nt][r] * rib[row];
                const float xv = Xb[(size_t)row * S_ + col];
                float* o = Ob + (size_t)row * 2048 + col;
                o[0]    = xv;
                o[512]  = at;
                o[1024] = xv - at;
                o[1536] = xv * at;
            }
        }
}

// ---------------------------------------------------------------------------
extern "C" void kernel_launch(void* const* d_in, const int* in_sizes, int n_in,
                              void* d_out, int out_size, void* d_ws, size_t ws_size,
                              hipStream_t stream)
{
    const float* A  = (const float*)d_in[0];   // a_bar [32,512,512]
    const float* Bm = (const float*)d_in[1];   // b_bar [32,512,512]
    float* Ma = (float*)d_out;                             // [32,512,2048]
    float* Mb = Ma + (size_t)B_ * S_ * 2048;               // [32,512,2048]

    // ws layout (~101 MB, unchanged footprint):
    float* E    = (float*)d_ws;
    float* Et   = E + (size_t)B_ * SxS;
    short* Va   = (short*)(Et + (size_t)B_ * SxS);         // V-plane from A
    short* Vb   = Va + (size_t)B_ * SxS;                   // V-plane from B
    float* rinv = (float*)(Vb + (size_t)B_ * SxS);
    float* cinv = rinv + B_ * S_;

    // PA/PB hi/lo planes are scratch in the OUTPUT buffer (dead after
    // k_gemm_e, fully overwritten by k_pv). 67 MB << 537 MB output.
    short* PA = (short*)d_out;
    short* PB = PA + (size_t)B_ * S_ * 1024;

    k_prep  <<<dim3(8, 8, 64), 256, 0, stream>>>(A, Bm, PA, PB, Va, Vb);
    k_gemm_e<<<dim3(4, 4, 32), 256, 0, stream>>>(PA, PB, E, Et);
    k_softp <<<dim3(4096, 2),  256, 0, stream>>>(E, Et, rinv, cinv);
    k_pv    <<<dim3(4, 4, 64), 256, 0, stream>>>(E, Et, rinv, cinv,
                                                 Va, Vb, A, Bm, Ma, Mb);
}

// Round 3
// 468.113 us; speedup vs baseline: 1.0261x; 1.0031x over previous
//
#include <hip/hip_runtime.h>
#include <hip/hip_bf16.h>
#include <math.h>

#define B_   32
#define S_   512
#define SxS  (S_ * S_)
#define LOG2E 1.4426950408889634f

using frag_ab = __attribute__((ext_vector_type(8))) short;   // 8 bf16 = 4 VGPR
using frag_cd = __attribute__((ext_vector_type(4))) float;   // 4 fp32 acc

__device__ inline short f2bf(float x) {
    __hip_bfloat16 h = __float2bfloat16(x);
    return *reinterpret_cast<short*>(&h);
}
__device__ inline float bf2f(short s) {
    __hip_bfloat16 h = *reinterpret_cast<__hip_bfloat16*>(&s);
    return __bfloat162float(h);
}
__device__ __forceinline__ int swz(int r) { return (r ^ (r >> 3)) & 7; }

// async global->LDS, 16B per lane. LDS dest must be wave-uniform base.
__device__ __forceinline__ void async16(const short* g, short* l) {
    __builtin_amdgcn_global_load_lds(
        (const __attribute__((address_space(1))) void*)g,
        (__attribute__((address_space(3))) void*)l,
        16, 0, 0);
}

// ---------------------------------------------------------------------------
// k_prep (unchanged from R2): reads A/B fp32 once. Produces:
//   1) PA/PB: packed hi/lo bf16 planes for the e-GEMM (PA pre-scaled LOG2E).
//   2) Va/Vb: bf16 transposed V-planes Vp[d][window W][chunk^(d&7)].
// ---------------------------------------------------------------------------
__global__ __launch_bounds__(256) void k_prep(const float* __restrict__ A,
                                              const float* __restrict__ Bm,
                                              short* __restrict__ PA,
                                              short* __restrict__ PB,
                                              short* __restrict__ Va,
                                              short* __restrict__ Vb)
{
    const int z   = blockIdx.z;          // 0..63
    const int b   = z & 31;
    const int isB = z >> 5;
    const float* X = (isB ? Bm : A) + (size_t)b * SxS;
    short* P  = (isB ? PB : PA) + (size_t)b * (S_ * 1024);
    short* Vp = (isB ? Vb : Va) + (size_t)b * SxS;
    const float scale = isB ? 1.0f : LOG2E;

    const int i0 = blockIdx.y * 64, d0 = blockIdx.x * 64;

    __shared__ short T[64][72];

    const int sl = threadIdx.x & 7;
    const int il = threadIdx.x >> 3;

    #pragma unroll
    for (int p = 0; p < 2; ++p) {
        const int i    = il + 32 * p;
        const int rowg = i0 + i;
        const float* src = X + (size_t)rowg * S_ + d0 + sl * 8;
        const float4 v0 = *(const float4*)(src);
        const float4 v1 = *(const float4*)(src + 4);

        T[sl * 8 + 0][i] = f2bf(v0.x); T[sl * 8 + 1][i] = f2bf(v0.y);
        T[sl * 8 + 2][i] = f2bf(v0.z); T[sl * 8 + 3][i] = f2bf(v0.w);
        T[sl * 8 + 4][i] = f2bf(v1.x); T[sl * 8 + 5][i] = f2bf(v1.y);
        T[sl * 8 + 6][i] = f2bf(v1.z); T[sl * 8 + 7][i] = f2bf(v1.w);

        const float xs[8] = {v0.x, v0.y, v0.z, v0.w, v1.x, v1.y, v1.z, v1.w};
        frag_ab hi, lo;
        #pragma unroll
        for (int j = 0; j < 8; ++j) {
            const float x = xs[j] * scale;
            const short h = f2bf(x);
            hi[j] = h;
            lo[j] = f2bf(x - bf2f(h));
        }
        const int W = (d0 >> 5) + (sl >> 2);
        const int q = sl & 3;
        short* base = P + (size_t)rowg * 1024 + W * 64;
        *(frag_ab*)(base + (((2 * q)     ^ (rowg & 7)) * 8)) = hi;
        *(frag_ab*)(base + (((2 * q + 1) ^ (rowg & 7)) * 8)) = lo;
    }
    __syncthreads();

    const int pc = threadIdx.x & 7, dl = threadIdx.x >> 3;
    #pragma unroll
    for (int p = 0; p < 2; ++p) {
        const int d  = dl + 32 * p;
        const int dg = d0 + d;
        frag_ab t = *(const frag_ab*)&T[d][pc * 8];
        *(frag_ab*)(Vp + (size_t)dg * 512 + i0 + ((pc ^ (dg & 7)) * 8)) = t;
    }
}

// ---------------------------------------------------------------------------
// e' = (LOG2E*A)·B^T via hi/lo bf16 MFMA. Writes E ONLY (Et eliminated).
// ---------------------------------------------------------------------------
__global__ __launch_bounds__(256) void k_gemm_e(const short* __restrict__ PA,
                                                const short* __restrict__ PB,
                                                float* __restrict__ E)
{
    const int lin     = blockIdx.x + (blockIdx.y << 2) + (blockIdx.z << 4);
    const int logical = ((lin & 7) << 6) + (lin >> 3);
    const int b  = logical >> 4;
    const int i0 = ((logical >> 2) & 3) * 128;
    const int j0 = (logical & 3) * 128;

    const short* Ab = PA + (size_t)b * (S_ * 1024);
    const short* Bb = PB + (size_t)b * (S_ * 1024);
    float* Eb = E + (size_t)b * SxS;

    __shared__ __align__(16) short As[128][64];
    __shared__ __align__(16) short Bs[128][64];

    const int tid  = threadIdx.x;
    const int wave = tid >> 6, lane = tid & 63;
    const int wr   = wave >> 1, wc = wave & 1;
    const int q    = lane >> 4, m = lane & 15;
    const int srow = lane >> 3, schunk = lane & 7;

    frag_cd zero = {0.f, 0.f, 0.f, 0.f};
    frag_cd acc[4][4];
    #pragma unroll
    for (int i = 0; i < 4; ++i)
        #pragma unroll
        for (int j = 0; j < 4; ++j) acc[i][j] = zero;

    for (int k0 = 0; k0 < S_; k0 += 32) {
        const int W = k0 >> 5;
        __syncthreads();
        #pragma unroll
        for (int p = 0; p < 4; ++p) {
            const int seg    = wave * 4 + p;
            const int rowg_a = i0 + seg * 8 + srow;
            const int rowg_b = j0 + seg * 8 + srow;
            async16(Ab + (size_t)rowg_a * 1024 + W * 64 + schunk * 8, &As[seg * 8][0]);
            async16(Bb + (size_t)rowg_b * 1024 + W * 64 + schunk * 8, &Bs[seg * 8][0]);
        }
        __syncthreads();

        frag_ab ah[4], al[4], bh[4], bl[4];
        #pragma unroll
        for (int t = 0; t < 4; ++t) {
            const int ra = wr * 64 + t * 16 + m;
            const int rb = wc * 64 + t * 16 + m;
            ah[t] = *(const frag_ab*)&As[ra][((2 * q)     ^ (ra & 7)) * 8];
            al[t] = *(const frag_ab*)&As[ra][((2 * q + 1) ^ (ra & 7)) * 8];
            bh[t] = *(const frag_ab*)&Bs[rb][((2 * q)     ^ (rb & 7)) * 8];
            bl[t] = *(const frag_ab*)&Bs[rb][((2 * q + 1) ^ (rb & 7)) * 8];
        }
        #pragma unroll
        for (int mt = 0; mt < 4; ++mt)
            #pragma unroll
            for (int nt = 0; nt < 4; ++nt) {
                acc[mt][nt] = __builtin_amdgcn_mfma_f32_16x16x32_bf16(ah[mt], bh[nt], acc[mt][nt], 0, 0, 0);
                acc[mt][nt] = __builtin_amdgcn_mfma_f32_16x16x32_bf16(ah[mt], bl[nt], acc[mt][nt], 0, 0, 0);
                acc[mt][nt] = __builtin_amdgcn_mfma_f32_16x16x32_bf16(al[mt], bh[nt], acc[mt][nt], 0, 0, 0);
            }
    }

    #pragma unroll
    for (int mt = 0; mt < 4; ++mt)
        #pragma unroll
        for (int nt = 0; nt < 4; ++nt) {
            const int rb  = i0 + wr * 64 + mt * 16 + q * 4;
            const int col = j0 + wc * 64 + nt * 16 + m;
            Eb[(size_t)(rb + 0) * S_ + col] = acc[mt][nt][0];
            Eb[(size_t)(rb + 1) * S_ + col] = acc[mt][nt][1];
            Eb[(size_t)(rb + 2) * S_ + col] = acc[mt][nt][2];
            Eb[(size_t)(rb + 3) * S_ + col] = acc[mt][nt][3];
        }
}

// ---------------------------------------------------------------------------
// k_pv_fused: per (side, b, strip of 64): softmax (row OR col of E) fully
// on-chip -> P bf16 in LDS (64x512), then C[64][512] = P·V with V staged
// via global_load_lds, fused 4-section epilogue. No P/stat HBM round-trip.
// ---------------------------------------------------------------------------
__global__ __launch_bounds__(512) void k_pv_fused(const float* __restrict__ E,
                                                  const short* __restrict__ Va,
                                                  const short* __restrict__ Vb,
                                                  const float* __restrict__ A,
                                                  const float* __restrict__ Bm,
                                                  float* __restrict__ Ma,
                                                  float* __restrict__ Mb)
{
    // bijective XCD swizzle over 512 blocks
    const int lin     = blockIdx.x;
    const int logical = ((lin & 7) << 6) + (lin >> 3);
    const int side = logical >> 8;
    const int b    = (logical >> 3) & 31;
    const int s0   = (logical & 7) * 64;     // row-strip (side0) / col-strip (side1)

    const float* Eb  = E + (size_t)b * SxS;
    const short* Vg  = (side ? Va : Vb) + (size_t)b * SxS;
    const float* Xb  = (side ? Bm : A) + (size_t)b * SxS;
    float* Ob = (side ? Mb : Ma) + (size_t)b * S_ * 2048;

    __shared__ __align__(16) short Pl[64][512];   // 64 KB: P rows x K (swizzled chunks)
    __shared__ __align__(16) short Vs[512][64];   // 64 KB: V d-rows x K-window
    __shared__ float riS[64];
    __shared__ float mS[64];

    float* scr  = (float*)&Vs[0][0];              // phase-1 scratch (col side)
    float* scr2 = scr + 4096;

    const int tid = threadIdx.x;

    // ---------------- Phase 1: softmax -> P in LDS ----------------
    if (side == 0) {
        // row strip: rows s0..s0+64, full 512 cols. 8 lanes per row.
        const int r = tid >> 3, sub = tid & 7;
        const float* er = Eb + (size_t)(s0 + r) * S_;

        float mx = -INFINITY;
        #pragma unroll
        for (int fi = 0; fi < 8; ++fi) {
            const float* p = er + sub * 8 + fi * 64;
            const float4 u  = *(const float4*)p;
            const float4 u2 = *(const float4*)(p + 4);
            mx = fmaxf(mx, fmaxf(fmaxf(u.x, u.y), fmaxf(u.z, u.w)));
            mx = fmaxf(mx, fmaxf(fmaxf(u2.x, u2.y), fmaxf(u2.z, u2.w)));
        }
        mx = fmaxf(mx, __shfl_xor(mx, 1));
        mx = fmaxf(mx, __shfl_xor(mx, 2));
        mx = fmaxf(mx, __shfl_xor(mx, 4));

        float s = 0.f;
        const int sl = (sub ^ swz(r)) * 8;
        #pragma unroll
        for (int fi = 0; fi < 8; ++fi) {
            const float* p = er + sub * 8 + fi * 64;
            const float4 u  = *(const float4*)p;
            const float4 u2 = *(const float4*)(p + 4);
            const float xs[8] = {u.x, u.y, u.z, u.w, u2.x, u2.y, u2.z, u2.w};
            frag_ab pb;
            #pragma unroll
            for (int j = 0; j < 8; ++j) {
                const float pv = exp2f(xs[j] - mx);
                s += pv;
                pb[j] = f2bf(pv);
            }
            *(frag_ab*)&Pl[r][fi * 64 + sl] = pb;
        }
        s += __shfl_xor(s, 1);
        s += __shfl_xor(s, 2);
        s += __shfl_xor(s, 4);
        if (sub == 0) riS[r] = 1.0f / s;
    } else {
        // col strip: cols s0..s0+64, full 512 rows. thread: i-bundle ib (8 rows),
        // 8 cols sub*8..+8. Stats need LDS tree over the 64 ib groups.
        const int ib = tid >> 3, sub = tid & 7;

        float pm[8];
        #pragma unroll
        for (int c = 0; c < 8; ++c) pm[c] = -INFINITY;
        #pragma unroll
        for (int ii = 0; ii < 8; ++ii) {
            const float* p = Eb + (size_t)(ib * 8 + ii) * S_ + s0 + sub * 8;
            const float4 u  = *(const float4*)p;
            const float4 u2 = *(const float4*)(p + 4);
            pm[0] = fmaxf(pm[0], u.x);  pm[1] = fmaxf(pm[1], u.y);
            pm[2] = fmaxf(pm[2], u.z);  pm[3] = fmaxf(pm[3], u.w);
            pm[4] = fmaxf(pm[4], u2.x); pm[5] = fmaxf(pm[5], u2.y);
            pm[6] = fmaxf(pm[6], u2.z); pm[7] = fmaxf(pm[7], u2.w);
        }
        #pragma unroll
        for (int c = 0; c < 8; ++c) scr[ib * 64 + sub * 8 + c] = pm[c];
        __syncthreads();
        {
            const int col = tid & 63, h = tid >> 6;
            float v = scr[(h * 8) * 64 + col];
            #pragma unroll
            for (int k = 1; k < 8; ++k) v = fmaxf(v, scr[(h * 8 + k) * 64 + col]);
            scr2[h * 64 + col] = v;
        }
        __syncthreads();
        if (tid < 64) {
            float v = scr2[tid];
            #pragma unroll
            for (int h = 1; h < 8; ++h) v = fmaxf(v, scr2[h * 64 + tid]);
            mS[tid] = v;
        }
        __syncthreads();

        float ps[8];
        frag_ab pb[8];
        #pragma unroll
        for (int c = 0; c < 8; ++c) ps[c] = 0.f;
        #pragma unroll
        for (int ii = 0; ii < 8; ++ii) {
            const float* p = Eb + (size_t)(ib * 8 + ii) * S_ + s0 + sub * 8;
            const float4 u  = *(const float4*)p;
            const float4 u2 = *(const float4*)(p + 4);
            const float xs[8] = {u.x, u.y, u.z, u.w, u2.x, u2.y, u2.z, u2.w};
            #pragma unroll
            for (int c = 0; c < 8; ++c) {
                const float pv = exp2f(xs[c] - mS[sub * 8 + c]);
                ps[c] += pv;
                pb[c][ii] = f2bf(pv);
            }
        }
        // P' writes: row = local col, K = i. bundle ib is contiguous 8 i's.
        #pragma unroll
        for (int c = 0; c < 8; ++c) {
            const int cl = sub * 8 + c;
            *(frag_ab*)&Pl[cl][(ib >> 3) * 64 + (((ib & 7) ^ swz(cl)) * 8)] = pb[c];
        }
        __syncthreads();
        #pragma unroll
        for (int c = 0; c < 8; ++c) scr[ib * 64 + sub * 8 + c] = ps[c];
        __syncthreads();
        {
            const int col = tid & 63, h = tid >> 6;
            float v = 0.f;
            #pragma unroll
            for (int k = 0; k < 8; ++k) v += scr[(h * 8 + k) * 64 + col];
            scr2[h * 64 + col] = v;
        }
        __syncthreads();
        if (tid < 64) {
            float v = 0.f;
            #pragma unroll
            for (int h = 0; h < 8; ++h) v += scr2[h * 64 + tid];
            riS[tid] = 1.0f / v;
        }
    }

    // ---------------- Phase 2: C[64][512] = P · V ----------------
    const int wv = tid >> 6, lane = tid & 63;
    const int q = lane >> 4, m = lane & 15;

    frag_cd zero = {0.f, 0.f, 0.f, 0.f};
    frag_cd acc[4][4];
    #pragma unroll
    for (int i = 0; i < 4; ++i)
        #pragma unroll
        for (int j = 0; j < 4; ++j) acc[i][j] = zero;

    for (int k0 = 0; k0 < S_; k0 += 64) {
        __syncthreads();                     // Pl/scratch settled; Vs free
        #pragma unroll
        for (int p = 0; p < 8; ++p) {
            const int d = p * 64 + wv * 8 + (lane >> 3);
            // verbatim copy: Vs inherits Va's (d&7) chunk swizzle
            async16(Vg + (size_t)d * 512 + k0 + (lane & 7) * 8,
                    &Vs[p * 64 + wv * 8][0]);
        }
        __syncthreads();                     // drain

        #pragma unroll
        for (int kk = 0; kk < 2; ++kk) {
            frag_ab af[4], bf[4];
            #pragma unroll
            for (int t = 0; t < 4; ++t) {
                const int row = t * 16 + m;
                af[t] = *(const frag_ab*)&Pl[row][k0 + (((kk * 4 + q) ^ swz(row)) * 8)];
                const int dl = wv * 64 + t * 16 + m;
                bf[t] = *(const frag_ab*)&Vs[dl][(((kk * 4 + q) ^ (dl & 7)) * 8)];
            }
            #pragma unroll
            for (int mt = 0; mt < 4; ++mt)
                #pragma unroll
                for (int nt = 0; nt < 4; ++nt)
                    acc[mt][nt] = __builtin_amdgcn_mfma_f32_16x16x32_bf16(af[mt], bf[nt], acc[mt][nt], 0, 0, 0);
        }
    }

    // ---------------- Epilogue ----------------
    #pragma unroll
    for (int mt = 0; mt < 4; ++mt)
        #pragma unroll
        for (int nt = 0; nt < 4; ++nt) {
            const int col = wv * 64 + nt * 16 + m;
            #pragma unroll
            for (int rr = 0; rr < 4; ++rr) {
                const int rl   = mt * 16 + q * 4 + rr;
                const int rowg = s0 + rl;
                const float at = acc[mt][nt][rr] * riS[rl];
                const float xv = Xb[(size_t)rowg * S_ + col];
                float* o = Ob + (size_t)rowg * 2048 + col;
                o[0]    = xv;
                o[512]  = at;
                o[1024] = xv - at;
                o[1536] = xv * at;
            }
        }
}

// ---------------------------------------------------------------------------
extern "C" void kernel_launch(void* const* d_in, const int* in_sizes, int n_in,
                              void* d_out, int out_size, void* d_ws, size_t ws_size,
                              hipStream_t stream)
{
    const float* A  = (const float*)d_in[0];   // a_bar [32,512,512]
    const float* Bm = (const float*)d_in[1];   // b_bar [32,512,512]
    float* Ma = (float*)d_out;                             // [32,512,2048]
    float* Mb = Ma + (size_t)B_ * S_ * 2048;               // [32,512,2048]

    // ws: E fp32 (33.5 MB) + Va/Vb bf16 (16.75 MB each) = ~67 MB
    float* E  = (float*)d_ws;
    short* Va = (short*)(E + (size_t)B_ * SxS);
    short* Vb = Va + (size_t)B_ * SxS;

    // PA/PB hi/lo planes scratch in the OUTPUT buffer (dead after k_gemm_e).
    short* PA = (short*)d_out;
    short* PB = PA + (size_t)B_ * S_ * 1024;

    k_prep    <<<dim3(8, 8, 64), 256, 0, stream>>>(A, Bm, PA, PB, Va, Vb);
    k_gemm_e  <<<dim3(4, 4, 32), 256, 0, stream>>>(PA, PB, E);
    k_pv_fused<<<dim3(512),      512, 0, stream>>>(E, Va, Vb, A, Bm, Ma, Mb);
}